// Round 2
// baseline (314.752 us; speedup 1.0000x reference)
//
#include <hip/hip_runtime.h>
#include <math.h>

// S4D scan, fp32.
// B=8, L=4096, H=512, N2=32 complex modes.
// Pair = (b,h): 4096 independent serial scans.
// Mapping: 16 lanes per pair, each lane owns modes (2*sub, 2*sub+1).
// Block = 256 threads = 16 pairs (contiguous h for one b). Grid = 256 blocks.
// Per step: pure FMA state update + per-lane partial C-dot -> LDS.
// Every TC=32 steps: vectorized flush (sum 16 partials + D*x + exact GELU).
// Final state written PLANAR: all real parts (B,H,N2) then all imag parts.

#define H_  512
#define L_  4096
#define B_  8
#define N2_ 32
#define TC  32
#define PPB 16           // pairs per block
#define THREADS 256
#define NCHUNK (L_ / TC)
#define YPAD 17          // padded stride for ldsY partials

__global__ __launch_bounds__(THREADS) void s4d_scan_kernel(
    const float* __restrict__ x,          // (B, L, H)
    const float* __restrict__ log_dt,     // (H,)
    const float* __restrict__ A_real_log, // (H, N2)
    const float* __restrict__ A_imag,     // (H, N2)
    const float* __restrict__ B_re,       // (H, N2)
    const float* __restrict__ B_im,       // (H, N2)
    const float* __restrict__ C_re,       // (H, N2)
    const float* __restrict__ C_im,       // (H, N2)
    const float* __restrict__ Dv,         // (H,)
    float* __restrict__ out_y,            // (B, L, H)
    float* __restrict__ st_re,            // (B, H, N2) float32 real plane
    float* __restrict__ st_im)            // (B, H, N2) float32 imag plane
{
    __shared__ float ldsX[TC * PPB];          // 2 KB: x tile [j][p]
    __shared__ float ldsY[TC * PPB * YPAD];   // ~34.8 KB: partials [(j*16+q)*17 + sub]

    const int tid  = threadIdx.x;
    const int sub  = tid & 15;        // lane within pair (owns modes 2*sub, 2*sub+1)
    const int q    = tid >> 4;        // pair within block
    const int pair = blockIdx.x * PPB + q;    // == b*H + h
    const int h    = pair & (H_ - 1);
    const int bblk = blockIdx.x >> 5;             // batch index (32 blocks per b)
    const int h0   = (blockIdx.x & 31) * PPB;     // block's h base

    // ---- per-lane constants (ZOH discretization), modes n0 = 2*sub, n1 = 2*sub+1 ----
    const float dt = expf(log_dt[h]);

    float dAr[2], dAi[2], dBr[2], dBi[2], C2r[2], C2i[2];
#pragma unroll
    for (int m = 0; m < 2; ++m) {
        const int n  = 2 * sub + m;
        const int hn = h * N2_ + n;
        const float Ar = -expf(A_real_log[hn]);
        const float Ai = A_imag[hn];
        const float xr = dt * Ar;
        const float xi = dt * Ai;
        const float ex = expf(xr);
        const float cs = cosf(xi);
        const float sn = sinf(xi);
        dAr[m] = ex * cs;
        dAi[m] = ex * sn;
        // expm1(xr + i*xi), cancellation-safe real part:
        const float sh  = sinf(0.5f * xi);
        const float emr = expm1f(xr) * cs - 2.0f * sh * sh;
        const float emi = ex * sn;
        // em / A  =  em * conj(A) / |A|^2
        const float inv = 1.0f / (Ar * Ar + Ai * Ai);
        const float tr  = (emr * Ar + emi * Ai) * inv;
        const float ti  = (emi * Ar - emr * Ai) * inv;
        // dB = (B_re + i B_im) * (tr + i ti)
        const float Br = B_re[hn], Bi = B_im[hn];
        dBr[m] = Br * tr - Bi * ti;
        dBi[m] = Br * ti + Bi * tr;
        C2r[m] = 2.0f * C_re[hn];
        C2i[m] = 2.0f * C_im[hn];
    }

    const float Dp = Dv[h0 + sub];    // D for the flush element this thread handles

    const float* __restrict__ xrow = x     + (size_t)bblk * L_ * H_ + h0;
    float*       __restrict__ yrow = out_y + (size_t)bblk * L_ * H_ + h0;

    const int j0 = tid >> 4;          // staging row (== q, but semantically t-offset)

    // prologue: prefetch chunk 0 into registers
    float rx0 = xrow[(size_t)(j0)      * H_ + sub];
    float rx1 = xrow[(size_t)(j0 + 16) * H_ + sub];

    float sr0 = 0.f, si0 = 0.f, sr1 = 0.f, si1 = 0.f;

    for (int c = 0; c < NCHUNK; ++c) {
        const int t0 = c * TC;

        __syncthreads();              // ldsX/ldsY free (flush of prev chunk done)
        ldsX[tid]           = rx0;
        ldsX[tid + THREADS] = rx1;
        __syncthreads();

        // prefetch next chunk (hides HBM latency under the scan body)
        if (c + 1 < NCHUNK) {
            rx0 = xrow[(size_t)(t0 + TC + j0)      * H_ + sub];
            rx1 = xrow[(size_t)(t0 + TC + j0 + 16) * H_ + sub];
        }

        // ---- serial scan over TC steps ----
#pragma unroll
        for (int j = 0; j < TC; ++j) {
            const float xv = ldsX[j * PPB + q];   // broadcast within the 16-lane pair
            const float t0r = fmaf(dAr[0], sr0, fmaf(-dAi[0], si0, dBr[0] * xv));
            const float t0i = fmaf(dAr[0], si0, fmaf( dAi[0], sr0, dBi[0] * xv));
            const float t1r = fmaf(dAr[1], sr1, fmaf(-dAi[1], si1, dBr[1] * xv));
            const float t1i = fmaf(dAr[1], si1, fmaf( dAi[1], sr1, dBi[1] * xv));
            sr0 = t0r; si0 = t0i; sr1 = t1r; si1 = t1i;
            // per-lane partial of 2*Re(C . state) over this lane's two modes
            const float part = fmaf(C2r[0], sr0,
                              fmaf(-C2i[0], si0,
                              fmaf(C2r[1], sr1, -(C2i[1] * si1))));
            ldsY[(j * PPB + q) * YPAD + sub] = part;
        }
        __syncthreads();

        // ---- flush: sum 16 partials per element, + D*x, exact GELU, store ----
#pragma unroll
        for (int r = 0; r < 2; ++r) {
            const int e    = tid + r * THREADS;    // element = (j = e>>4, p = e&15 == sub)
            const int base = e * YPAD;
            float s = 0.f;
#pragma unroll
            for (int k = 0; k < 16; ++k) s += ldsY[base + k];
            const float xv = ldsX[e];
            const float y  = fmaf(Dp, xv, s);
            const float g  = 0.5f * y * (1.0f + erff(y * 0.70710678118654752f));
            yrow[(size_t)(t0 + (e >> 4)) * H_ + sub] = g;
        }
        __syncthreads();
    }

    // ---- final state: PLANAR float32 — re plane (B,H,N2), then im plane ----
    // lane sub owns modes 2*sub, 2*sub+1 -> contiguous float2 in each plane
    float2* rp = (float2*)(st_re + (size_t)pair * N2_);
    float2* ip = (float2*)(st_im + (size_t)pair * N2_);
    rp[sub] = make_float2(sr0, sr1);
    ip[sub] = make_float2(si0, si1);
}

extern "C" void kernel_launch(void* const* d_in, const int* in_sizes, int n_in,
                              void* d_out, int out_size, void* d_ws, size_t ws_size,
                              hipStream_t stream) {
    (void)in_sizes; (void)n_in; (void)d_ws; (void)ws_size; (void)out_size;
    const float* x    = (const float*)d_in[0];
    const float* ldt  = (const float*)d_in[1];
    const float* Arl  = (const float*)d_in[2];
    const float* Aim  = (const float*)d_in[3];
    const float* Bre  = (const float*)d_in[4];
    const float* Bim  = (const float*)d_in[5];
    const float* Cre  = (const float*)d_in[6];
    const float* Cim  = (const float*)d_in[7];
    const float* Dv   = (const float*)d_in[8];
    float* out = (float*)d_out;
    float* st_re = out + (size_t)B_ * L_ * H_;       // ys first
    float* st_im = st_re + (size_t)B_ * H_ * N2_;    // then imag plane

    dim3 grid(B_ * H_ / PPB);   // 256 blocks
    dim3 block(THREADS);        // 256 threads
    hipLaunchKernelGGL(s4d_scan_kernel, grid, block, 0, stream,
                       x, ldt, Arl, Aim, Bre, Bim, Cre, Cim, Dv, out, st_re, st_im);
}

// Round 3
// 306.756 us; speedup vs baseline: 1.0261x; 1.0261x over previous
//
#include <hip/hip_runtime.h>
#include <math.h>

// S4D scan, fp32 — round 3: 1 complex mode per lane => 2 waves/SIMD.
// B=8, L=4096, H=512, N2=32 complex modes. 4096 independent (b,h) scans.
// Mapping: 32 lanes per pair (lane sub owns mode n=sub). Block = 256 thr =
// 8 pairs. Grid = 512 blocks = 2 blocks/CU = 8 waves/CU = 2 waves/SIMD.
// Per step: 8 VALU (state update + partial C-dot) + ds_read(x) + ds_write(part).
// Every TC=32 steps: flush — sum 32 partials + D*x + exact GELU, store.
// Final state PLANAR float32: re plane (B,H,N2), then im plane.

#define H_  512
#define L_  4096
#define B_  8
#define N2_ 32
#define TC  32
#define PPB 8            // pairs per block
#define THREADS 256
#define NCHUNK (L_ / TC)
#define YSTR 33          // ldsY stride: bank=(e+sub)%32 -> worst 2-way (free)

__global__ __launch_bounds__(THREADS) void s4d_scan_kernel(
    const float* __restrict__ x,          // (B, L, H)
    const float* __restrict__ log_dt,     // (H,)
    const float* __restrict__ A_real_log, // (H, N2)
    const float* __restrict__ A_imag,     // (H, N2)
    const float* __restrict__ B_re,       // (H, N2)
    const float* __restrict__ B_im,       // (H, N2)
    const float* __restrict__ C_re,       // (H, N2)
    const float* __restrict__ C_im,       // (H, N2)
    const float* __restrict__ Dv,         // (H,)
    float* __restrict__ out_y,            // (B, L, H)
    float* __restrict__ st_re,            // (B, H, N2) real plane
    float* __restrict__ st_im)            // (B, H, N2) imag plane
{
    __shared__ float ldsX[TC * PPB];            // 1 KB: x tile, elem e=(j*8+p)
    __shared__ float ldsY[TC * PPB * YSTR];     // 33 KB: partials [e*33 + sub]

    const int tid  = threadIdx.x;
    const int sub  = tid & 31;        // mode index n = sub
    const int q    = tid >> 5;        // pair within block (0..7)
    const int pair = blockIdx.x * PPB + q;        // == b*H + h
    const int h    = pair & (H_ - 1);
    const int bblk = blockIdx.x >> 6;             // 64 blocks per batch
    const int h0   = (blockIdx.x & 63) * PPB;     // block's h base

    // ---- per-lane constants (ZOH discretization), mode n = sub ----
    const float dt = expf(log_dt[h]);
    const int hn = h * N2_ + sub;
    const float Ar = -expf(A_real_log[hn]);
    const float Ai = A_imag[hn];
    const float xr = dt * Ar;
    const float xi = dt * Ai;
    const float ex = expf(xr);
    const float cs = cosf(xi);
    const float sn = sinf(xi);
    const float dAr = ex * cs;
    const float dAi = ex * sn;
    // expm1(xr + i*xi), cancellation-safe real part:
    const float sh  = sinf(0.5f * xi);
    const float emr = expm1f(xr) * cs - 2.0f * sh * sh;
    const float emi = ex * sn;
    // em / A = em * conj(A) / |A|^2
    const float inv = 1.0f / (Ar * Ar + Ai * Ai);
    const float tr  = (emr * Ar + emi * Ai) * inv;
    const float ti  = (emi * Ar - emr * Ai) * inv;
    const float Br = B_re[hn], Bi = B_im[hn];
    const float dBr = Br * tr - Bi * ti;
    const float dBi = Br * ti + Bi * tr;
    const float C2r  = 2.0f * C_re[hn];
    const float nC2i = -2.0f * C_im[hn];

    // flush constants: this thread flushes element e = tid -> (j=e>>3, p=e&7)
    const float Dp = Dv[h0 + (tid & 7)];

    const float* __restrict__ xrow = x     + (size_t)bblk * L_ * H_ + h0;
    float*       __restrict__ yrow = out_y + (size_t)bblk * L_ * H_ + h0;

    const int j0 = tid >> 3;          // staging row this thread loads
    const int p0 = tid & 7;           // staging h-offset

    // prologue: prefetch chunk 0 (1 element per thread per chunk)
    float rx = xrow[(size_t)j0 * H_ + p0];

    float sr = 0.f, si = 0.f;

    for (int c = 0; c < NCHUNK; ++c) {
        const int t0 = c * TC;

        __syncthreads();              // ldsX/ldsY free (prev flush done)
        ldsX[tid] = rx;
        __syncthreads();

        // prefetch next chunk (hides HBM latency under the scan body)
        if (c + 1 < NCHUNK) {
            rx = xrow[(size_t)(t0 + TC + j0) * H_ + p0];
        }

        // ---- serial scan over TC steps ----
#pragma unroll
        for (int j = 0; j < TC; ++j) {
            const float xv = ldsX[j * PPB + q];   // broadcast within pair
            const float nr = fmaf(dAr, sr, fmaf(-dAi, si, dBr * xv));
            const float ni = fmaf(dAr, si, fmaf( dAi, sr, dBi * xv));
            sr = nr; si = ni;
            // per-lane partial of 2*Re(C_n * s_n)
            const float part = fmaf(C2r, sr, nC2i * si);
            ldsY[(j * PPB + q) * YSTR + sub] = part;
        }
        __syncthreads();

        // ---- flush: sum 32 partials per element, + D*x, exact GELU, store ----
        {
            const int e    = tid;                  // element (j = e>>3, p = e&7)
            const int base = e * YSTR;
            float s = 0.f;
#pragma unroll
            for (int k = 0; k < 32; ++k) s += ldsY[base + k];
            const float xv = ldsX[e];
            const float y  = fmaf(Dp, xv, s);
            const float g  = 0.5f * y * (1.0f + erff(y * 0.70710678118654752f));
            yrow[(size_t)(t0 + (e >> 3)) * H_ + (e & 7)] = g;
        }
        __syncthreads();
    }

    // ---- final state: PLANAR float32 — re plane (B,H,N2), then im plane ----
    st_re[(size_t)pair * N2_ + sub] = sr;
    st_im[(size_t)pair * N2_ + sub] = si;
}

extern "C" void kernel_launch(void* const* d_in, const int* in_sizes, int n_in,
                              void* d_out, int out_size, void* d_ws, size_t ws_size,
                              hipStream_t stream) {
    (void)in_sizes; (void)n_in; (void)d_ws; (void)ws_size; (void)out_size;
    const float* x    = (const float*)d_in[0];
    const float* ldt  = (const float*)d_in[1];
    const float* Arl  = (const float*)d_in[2];
    const float* Aim  = (const float*)d_in[3];
    const float* Bre  = (const float*)d_in[4];
    const float* Bim  = (const float*)d_in[5];
    const float* Cre  = (const float*)d_in[6];
    const float* Cim  = (const float*)d_in[7];
    const float* Dv   = (const float*)d_in[8];
    float* out = (float*)d_out;
    float* st_re = out + (size_t)B_ * L_ * H_;       // ys first
    float* st_im = st_re + (size_t)B_ * H_ * N2_;    // then imag plane

    dim3 grid(B_ * H_ / PPB);   // 512 blocks
    dim3 block(THREADS);        // 256 threads
    hipLaunchKernelGGL(s4d_scan_kernel, grid, block, 0, stream,
                       x, ldt, Arl, Aim, Bre, Bim, Cre, Cim, Dv, out, st_re, st_im);
}

// Round 4
// 303.643 us; speedup vs baseline: 1.0366x; 1.0103x over previous
//
#include <hip/hip_runtime.h>
#include <math.h>

// S4D scan, fp32 — round 4: register scan + DPP quad-reduction.
// B=8, L=4096, H=512, N2=32. 4096 independent (b,h) scans, 32 lanes/pair.
// Track u = 2C*s (fold output proj into state): 6 VALU/step, partial = Re(u).
// x tile transposed [pair][t], double-buffered; scan reads x via 8 broadcast
// ds_read_b128 per 32-step chunk -> step loop is pure registers + 1 narrow
// ds_write of DPP quad-sums (16/64 lanes). Flush: 8 adds + D*x + GELU.
// Final state s = u*conj(2C)/|2C|^2, planar (re plane then im plane).

#define H_  512
#define L_  4096
#define B_  8
#define N2_ 32
#define TC  32
#define PPB 16           // pairs per block
#define THREADS 512
#define NCHUNK (L_ / TC) // 128
#define XSTR 36          // x-tile row stride (floats): 144 B, 16B-aligned rows
#define YSTR 9           // quad-sums per element (8) + 1 pad

template <int CTRL>
__device__ __forceinline__ float dpp_add(float v) {
    // v + (v shifted right by CTRL lanes within row16, 0-fill at row edge)
    int s = __builtin_amdgcn_update_dpp(0, __float_as_int(v), CTRL, 0xf, 0xf, true);
    return v + __int_as_float(s);
}

__global__ __launch_bounds__(THREADS) void s4d_scan_kernel(
    const float* __restrict__ x,          // (B, L, H)
    const float* __restrict__ log_dt,     // (H,)
    const float* __restrict__ A_real_log, // (H, N2)
    const float* __restrict__ A_imag,     // (H, N2)
    const float* __restrict__ B_re,       // (H, N2)
    const float* __restrict__ B_im,       // (H, N2)
    const float* __restrict__ C_re,       // (H, N2)
    const float* __restrict__ C_im,       // (H, N2)
    const float* __restrict__ Dv,         // (H,)
    float* __restrict__ out_y,            // (B, L, H)
    float* __restrict__ st_re,            // (B, H, N2) real plane
    float* __restrict__ st_im)            // (B, H, N2) imag plane
{
    __shared__ __align__(16) float ldsX[2][PPB * XSTR];  // 2 x 2304 B, [p][t]
    __shared__ float ldsY[TC * PPB * YSTR];              // 18.4 KB quad-sums

    const int tid  = threadIdx.x;
    const int sub  = tid & 31;        // mode index n = sub
    const int q    = tid >> 5;        // pair within block (0..15)
    const int pair = blockIdx.x * PPB + q;        // == b*H + h
    const int h    = pair & (H_ - 1);
    const int bblk = blockIdx.x >> 5;             // 32 blocks per batch
    const int h0   = (blockIdx.x & 31) * PPB;     // block's h base

    // ---- per-lane constants (ZOH), mode n = sub; fold w = 2C into state ----
    const float dt = expf(log_dt[h]);
    const int hn = h * N2_ + sub;
    const float Ar = -expf(A_real_log[hn]);
    const float Ai = A_imag[hn];
    const float xr = dt * Ar;
    const float xi = dt * Ai;
    const float ex = expf(xr);
    const float cs = cosf(xi);
    const float sn = sinf(xi);
    const float dAr = ex * cs;
    const float dAi = ex * sn;
    // expm1(dtA)/A, cancellation-safe real part of expm1:
    const float sh  = sinf(0.5f * xi);
    const float emr = expm1f(xr) * cs - 2.0f * sh * sh;
    const float emi = ex * sn;
    const float ia  = 1.0f / (Ar * Ar + Ai * Ai);
    const float tr  = (emr * Ar + emi * Ai) * ia;
    const float ti  = (emi * Ar - emr * Ai) * ia;
    // dB = B * (tr,ti);  dB2 = w * dB,  w = 2C
    const float Br = B_re[hn], Bi = B_im[hn];
    const float dBr = Br * tr - Bi * ti;
    const float dBi = Br * ti + Bi * tr;
    const float wr = 2.0f * C_re[hn];
    const float wi = 2.0f * C_im[hn];
    const float dB2r = wr * dBr - wi * dBi;
    const float dB2i = wr * dBi + wi * dBr;

    const float Dp = Dv[h0 + (tid & 15)];   // D for this thread's flush element

    const float* __restrict__ xrow = x     + (size_t)bblk * L_ * H_ + h0;
    float*       __restrict__ yrow = out_y + (size_t)bblk * L_ * H_ + h0;

    const int j0 = tid >> 4;          // staging t-offset (0..31)
    const int p0 = tid & 15;          // staging h-offset

    // ---- prologue: stage chunk 0, prefetch chunk 1 ----
    float rxA = xrow[(size_t)j0 * H_ + p0];
    ldsX[0][p0 * XSTR + j0] = rxA;
    if (NCHUNK > 1) rxA = xrow[(size_t)(TC + j0) * H_ + p0];
    __syncthreads();

    float ur = 0.f, ui = 0.f;

    for (int c = 0; c < NCHUNK; ++c) {
        const int cb = c & 1;
        const int t0 = c * TC;

        // stage next chunk's x (loaded last iter; vmcnt long since covered)
        if (c + 1 < NCHUNK) ldsX[cb ^ 1][p0 * XSTR + j0] = rxA;
        // issue global load for chunk c+2
        if (c + 2 < NCHUNK) rxA = xrow[(size_t)((c + 2) * TC + j0) * H_ + p0];

        // pull this chunk's 32 x-values into registers (broadcast b128 reads)
        float4 a[8];
        const float4* xq = (const float4*)&ldsX[cb][q * XSTR];
#pragma unroll
        for (int i = 0; i < 8; ++i) a[i] = xq[i];

        // ---- serial scan over TC steps: pure registers + narrow ds_write ----
#pragma unroll
        for (int j = 0; j < TC; ++j) {
            const float4 t4 = a[j >> 2];
            const float xv = ((j & 3) == 0) ? t4.x :
                             ((j & 3) == 1) ? t4.y :
                             ((j & 3) == 2) ? t4.z : t4.w;
            const float nr = fmaf(dAr, ur, fmaf(-dAi, ui, dB2r * xv));
            const float ni = fmaf(dAr, ui, fmaf( dAi, ur, dB2i * xv));
            ur = nr; ui = ni;
            // quad-sum of Re(u) via 2 DPP adds (VALU pipe, no LDS)
            const float s1 = dpp_add<0x111>(ur);   // + row_shr:1
            const float s2 = dpp_add<0x112>(s1);   // + row_shr:2
            if ((sub & 3) == 3)
                ldsY[(j * PPB + q) * YSTR + (sub >> 2)] = s2;
        }
        __syncthreads();   // A: ldsY quad-sums visible; next x-tile staged

        // ---- flush: 8 quad-sums + D*x, exact GELU, coalesced store ----
        {
            const int e    = tid;                  // (t = e>>4, p = e&15)
            const int base = e * YSTR;
            float s = 0.f;
#pragma unroll
            for (int k = 0; k < 8; ++k) s += ldsY[base + k];
            const float xv = ldsX[cb][(e & 15) * XSTR + (e >> 4)];
            const float y  = fmaf(Dp, xv, s);
            const float g  = 0.5f * y * (1.0f + erff(y * 0.70710678118654752f));
            yrow[(size_t)(t0 + (e >> 4)) * H_ + (e & 15)] = g;
        }
        __syncthreads();   // B: flush reads done; ldsY/ldsX[cb] reusable
    }

    // ---- final state: s = u * conj(w) / |w|^2, planar re/im ----
    const float iw = 1.0f / (wr * wr + wi * wi);
    const float sr = (ur * wr + ui * wi) * iw;
    const float si = (ui * wr - ur * wi) * iw;
    st_re[(size_t)pair * N2_ + sub] = sr;
    st_im[(size_t)pair * N2_ + sub] = si;
}

extern "C" void kernel_launch(void* const* d_in, const int* in_sizes, int n_in,
                              void* d_out, int out_size, void* d_ws, size_t ws_size,
                              hipStream_t stream) {
    (void)in_sizes; (void)n_in; (void)d_ws; (void)ws_size; (void)out_size;
    const float* x    = (const float*)d_in[0];
    const float* ldt  = (const float*)d_in[1];
    const float* Arl  = (const float*)d_in[2];
    const float* Aim  = (const float*)d_in[3];
    const float* Bre  = (const float*)d_in[4];
    const float* Bim  = (const float*)d_in[5];
    const float* Cre  = (const float*)d_in[6];
    const float* Cim  = (const float*)d_in[7];
    const float* Dv   = (const float*)d_in[8];
    float* out = (float*)d_out;
    float* st_re = out + (size_t)B_ * L_ * H_;       // ys first
    float* st_im = st_re + (size_t)B_ * H_ * N2_;    // then imag plane

    dim3 grid(B_ * H_ / PPB);   // 256 blocks (1 per CU), 8 waves each
    dim3 block(THREADS);        // 512 threads
    hipLaunchKernelGGL(s4d_scan_kernel, grid, block, 0, stream,
                       x, ldt, Arl, Aim, Bre, Bim, Cre, Cim, Dv, out, st_re, st_im);
}

// Round 5
// 262.187 us; speedup vs baseline: 1.2005x; 1.1581x over previous
//
#include <hip/hip_runtime.h>
#include <math.h>

// S4D scan, fp32 — round 5: pure-register scan + per-chunk butterfly reduce.
// B=8, L=4096, H=512, N2=32. 4096 (b,h) scans, 32 lanes/pair, 2 pairs/wave.
// Step body: 6 VALU only (u = dA*u + (2C*dB)*x, p[j]=Re(u)). No LDS/DPP/exec
// changes inside the step loop. Per 32-step chunk: 5-stage distributed
// transpose-reduce (DPP quad_perm for xor1/2, ds_swizzle for xor4/8/16);
// lane s ends with y-sum for t=t0+s -> D*x + exact GELU -> LDS transpose ->
// coalesced store. One barrier per chunk (double-buffered X and YT tiles).
// Final state s = u*conj(2C)/|2C|^2, planar (re plane, then im plane).

#define H_  512
#define L_  4096
#define B_  8
#define N2_ 32
#define TC  32
#define PPB 16           // pairs per block
#define THREADS 512
#define NCHUNK (L_ / TC) // 128
#define XSTR 36          // x-tile row stride (floats), 16B-aligned rows
#define YTSTR 33         // y-transpose tile row stride

__device__ __forceinline__ float bfly1(float v) {   // xor 1: quad_perm [1,0,3,2]
    return __int_as_float(__builtin_amdgcn_update_dpp(
        0, __float_as_int(v), 0xB1, 0xf, 0xf, true));
}
__device__ __forceinline__ float bfly2(float v) {   // xor 2: quad_perm [2,3,0,1]
    return __int_as_float(__builtin_amdgcn_update_dpp(
        0, __float_as_int(v), 0x4E, 0xf, 0xf, true));
}
template <int M>
__device__ __forceinline__ float bflyswz(float v) { // xor M within 32 lanes
    return __int_as_float(__builtin_amdgcn_ds_swizzle(
        __float_as_int(v), (M << 10) | 0x1F));
}

__global__ __launch_bounds__(THREADS, 2) void s4d_scan_kernel(
    const float* __restrict__ x,          // (B, L, H)
    const float* __restrict__ log_dt,     // (H,)
    const float* __restrict__ A_real_log, // (H, N2)
    const float* __restrict__ A_imag,     // (H, N2)
    const float* __restrict__ B_re,       // (H, N2)
    const float* __restrict__ B_im,       // (H, N2)
    const float* __restrict__ C_re,       // (H, N2)
    const float* __restrict__ C_im,       // (H, N2)
    const float* __restrict__ Dv,         // (H,)
    float* __restrict__ out_y,            // (B, L, H)
    float* __restrict__ st_re,            // (B, H, N2) real plane
    float* __restrict__ st_im)            // (B, H, N2) imag plane
{
    __shared__ __align__(16) float ldsX[2][PPB * XSTR];   // 2 x 2.3 KB, [p][t]
    __shared__ float ldsYT[2][PPB * YTSTR];               // 2 x 2.1 KB, [q][t]

    const int tid  = threadIdx.x;
    const int sub  = tid & 31;        // mode index during scan; t-offset after
    const int q    = tid >> 5;        // pair within block (0..15)
    const int pair = blockIdx.x * PPB + q;        // == b*H + h
    const int h    = pair & (H_ - 1);
    const int bblk = blockIdx.x >> 5;             // 32 blocks per batch
    const int h0   = (blockIdx.x & 31) * PPB;     // block's h base

    // ---- per-lane constants (ZOH), mode n = sub; fold w = 2C into state ----
    const float dt = expf(log_dt[h]);
    const int hn = h * N2_ + sub;
    const float Ar = -expf(A_real_log[hn]);
    const float Ai = A_imag[hn];
    const float xr = dt * Ar;
    const float xi = dt * Ai;
    const float ex = expf(xr);
    const float cs = cosf(xi);
    const float sn = sinf(xi);
    const float dAr = ex * cs;
    const float dAi = ex * sn;
    // expm1(dtA)/A, cancellation-safe real part of expm1:
    const float sh  = sinf(0.5f * xi);
    const float emr = expm1f(xr) * cs - 2.0f * sh * sh;
    const float emi = ex * sn;
    const float ia  = 1.0f / (Ar * Ar + Ai * Ai);
    const float tr  = (emr * Ar + emi * Ai) * ia;
    const float ti  = (emi * Ar - emr * Ai) * ia;
    const float Br = B_re[hn], Bi = B_im[hn];
    const float dBr = Br * tr - Bi * ti;
    const float dBi = Br * ti + Bi * tr;
    const float wr = 2.0f * C_re[hn];
    const float wi = 2.0f * C_im[hn];
    const float dB2r = wr * dBr - wi * dBi;
    const float dB2i = wr * dBi + wi * dBr;

    const float Dh = Dv[h];           // lane covers (pair q, t=t0+sub) at flush

    const float* __restrict__ xrow = x     + (size_t)bblk * L_ * H_ + h0;
    float*       __restrict__ yrow = out_y + (size_t)bblk * L_ * H_ + h0;

    const int j0 = tid >> 4;          // staging t-offset (0..31)
    const int p0 = tid & 15;          // staging h-offset

    // ---- prologue: stage chunk 0, prefetch chunk 1 ----
    float rx = xrow[(size_t)j0 * H_ + p0];
    ldsX[0][p0 * XSTR + j0] = rx;
    rx = xrow[(size_t)(TC + j0) * H_ + p0];
    __syncthreads();

    float ur = 0.f, ui = 0.f;

    const bool b1 = (sub & 1), b2 = (sub & 2), b4 = (sub & 4),
               b8 = (sub & 8), b16 = (sub & 16);

    for (int c = 0; c < NCHUNK; ++c) {
        const int cb = c & 1;

        // stage next chunk's x; issue global load for chunk c+2
        if (c + 1 < NCHUNK) ldsX[cb ^ 1][p0 * XSTR + j0] = rx;
        if (c + 2 < NCHUNK) rx = xrow[(size_t)((c + 2) * TC + j0) * H_ + p0];

        // pull this chunk's 32 x-values into registers (broadcast b128 reads)
        float4 a[8];
        const float4* xq = (const float4*)&ldsX[cb][q * XSTR];
#pragma unroll
        for (int i = 0; i < 8; ++i) a[i] = xq[i];

        // ---- serial scan over TC steps: registers only, 6 VALU/step ----
        float p[TC];
#pragma unroll
        for (int j = 0; j < TC; ++j) {
            const float4 t4 = a[j >> 2];
            const float xv = ((j & 3) == 0) ? t4.x :
                             ((j & 3) == 1) ? t4.y :
                             ((j & 3) == 2) ? t4.z : t4.w;
            const float nr = fmaf(dAr, ur, fmaf(-dAi, ui, dB2r * xv));
            const float ni = fmaf(dAr, ui, fmaf( dAi, ur, dB2i * xv));
            ur = nr; ui = ni;
            p[j] = ur;                 // Re(u) = this mode's y-contribution
        }

        // ---- 5-stage distributed transpose-reduce across the 32 lanes ----
        // After stage m, surviving slot j holds partial for logical index
        // with bit m = lane bit m. Final: p[0] = y-sum for t = t0 + sub.
#pragma unroll
        for (int j = 0; j < 32; j += 2) {
            const float keep = b1 ? p[j + 1] : p[j];
            const float send = b1 ? p[j] : p[j + 1];
            p[j] = keep + bfly1(send);
        }
#pragma unroll
        for (int j = 0; j < 32; j += 4) {
            const float keep = b2 ? p[j + 2] : p[j];
            const float send = b2 ? p[j] : p[j + 2];
            p[j] = keep + bfly2(send);
        }
#pragma unroll
        for (int j = 0; j < 32; j += 8) {
            const float keep = b4 ? p[j + 4] : p[j];
            const float send = b4 ? p[j] : p[j + 4];
            p[j] = keep + bflyswz<4>(send);
        }
#pragma unroll
        for (int j = 0; j < 32; j += 16) {
            const float keep = b8 ? p[j + 8] : p[j];
            const float send = b8 ? p[j] : p[j + 8];
            p[j] = keep + bflyswz<8>(send);
        }
        {
            const float keep = b16 ? p[16] : p[0];
            const float send = b16 ? p[0] : p[16];
            p[0] = keep + bflyswz<16>(send);
        }

        // ---- epilogue: lane (q, t=t0+sub): + D*x, exact GELU, LDS transpose
        {
            const float xv = ldsX[cb][q * XSTR + sub];
            const float y  = fmaf(Dh, xv, p[0]);
            const float g  = 0.5f * y * (1.0f + erff(y * 0.70710678118654752f));
            ldsYT[cb][q * YTSTR + sub] = g;
        }
        __syncthreads();   // YT visible; next x-tile staged; prev reads done

        // coalesced y store: thread e -> (t = e>>4, p = e&15)
        yrow[(size_t)(c * TC + (tid >> 4)) * H_ + (tid & 15)] =
            ldsYT[cb][(tid & 15) * YTSTR + (tid >> 4)];
    }

    // ---- final state: s = u * conj(w) / |w|^2, planar re/im ----
    const float iw = 1.0f / (wr * wr + wi * wi);
    const float sr = (ur * wr + ui * wi) * iw;
    const float si = (ui * wr - ur * wi) * iw;
    st_re[(size_t)pair * N2_ + sub] = sr;
    st_im[(size_t)pair * N2_ + sub] = si;
}

extern "C" void kernel_launch(void* const* d_in, const int* in_sizes, int n_in,
                              void* d_out, int out_size, void* d_ws, size_t ws_size,
                              hipStream_t stream) {
    (void)in_sizes; (void)n_in; (void)d_ws; (void)ws_size; (void)out_size;
    const float* x    = (const float*)d_in[0];
    const float* ldt  = (const float*)d_in[1];
    const float* Arl  = (const float*)d_in[2];
    const float* Aim  = (const float*)d_in[3];
    const float* Bre  = (const float*)d_in[4];
    const float* Bim  = (const float*)d_in[5];
    const float* Cre  = (const float*)d_in[6];
    const float* Cim  = (const float*)d_in[7];
    const float* Dv   = (const float*)d_in[8];
    float* out = (float*)d_out;
    float* st_re = out + (size_t)B_ * L_ * H_;       // ys first
    float* st_im = st_re + (size_t)B_ * H_ * N2_;    // then imag plane

    dim3 grid(B_ * H_ / PPB);   // 256 blocks (1 per CU), 8 waves each
    dim3 block(THREADS);        // 512 threads
    hipLaunchKernelGGL(s4d_scan_kernel, grid, block, 0, stream,
                       x, ldt, Arl, Aim, Bre, Bim, Cre, Cim, Dv, out, st_re, st_im);
}

// Round 6
// 253.783 us; speedup vs baseline: 1.2402x; 1.0331x over previous
//
#include <hip/hip_runtime.h>
#include <math.h>

// S4D scan, fp32 — round 6: VOP3P packed-fp32 scan step (3 x v_pk_fma/mul
// per step via inline asm with op_sel/neg_lo), butterfly reduce unchanged,
// sigmoid-form GELU. B=8, L=4096, H=512, N2=32; 32 lanes/pair, 2 pairs/wave,
// 512-thr blocks, 256 blocks (2 waves/SIMD).
// Final state s = u*conj(2C)/|2C|^2, planar (re plane, then im plane).

#define H_  512
#define L_  4096
#define B_  8
#define N2_ 32
#define TC  32
#define PPB 16           // pairs per block
#define THREADS 512
#define NCHUNK (L_ / TC) // 128
#define XSTR 36          // x-tile row stride (floats), 16B-aligned rows
#define YTSTR 33         // y-transpose tile row stride

typedef float v2f __attribute__((ext_vector_type(2)));
typedef float v4f __attribute__((ext_vector_type(4)));

__device__ __forceinline__ float bfly1(float v) {   // xor 1: quad_perm [1,0,3,2]
    return __int_as_float(__builtin_amdgcn_update_dpp(
        0, __float_as_int(v), 0xB1, 0xf, 0xf, true));
}
__device__ __forceinline__ float bfly2(float v) {   // xor 2: quad_perm [2,3,0,1]
    return __int_as_float(__builtin_amdgcn_update_dpp(
        0, __float_as_int(v), 0x4E, 0xf, 0xf, true));
}
template <int M>
__device__ __forceinline__ float bflyswz(float v) { // xor M within 32 lanes
    return __int_as_float(__builtin_amdgcn_ds_swizzle(
        __float_as_int(v), (M << 10) | 0x1F));
}

__global__ __launch_bounds__(THREADS, 2) void s4d_scan_kernel(
    const float* __restrict__ x,          // (B, L, H)
    const float* __restrict__ log_dt,     // (H,)
    const float* __restrict__ A_real_log, // (H, N2)
    const float* __restrict__ A_imag,     // (H, N2)
    const float* __restrict__ B_re,       // (H, N2)
    const float* __restrict__ B_im,       // (H, N2)
    const float* __restrict__ C_re,       // (H, N2)
    const float* __restrict__ C_im,       // (H, N2)
    const float* __restrict__ Dv,         // (H,)
    float* __restrict__ out_y,            // (B, L, H)
    float* __restrict__ st_re,            // (B, H, N2) real plane
    float* __restrict__ st_im)            // (B, H, N2) imag plane
{
    __shared__ __align__(16) float ldsX[2][PPB * XSTR];   // 2 x 2.3 KB, [p][t]
    __shared__ float ldsYT[2][PPB * YTSTR];               // 2 x 2.1 KB, [q][t]

    const int tid  = threadIdx.x;
    const int sub  = tid & 31;        // mode index during scan; t-offset after
    const int q    = tid >> 5;        // pair within block (0..15)
    const int pair = blockIdx.x * PPB + q;        // == b*H + h
    const int h    = pair & (H_ - 1);
    const int bblk = blockIdx.x >> 5;             // 32 blocks per batch
    const int h0   = (blockIdx.x & 31) * PPB;     // block's h base

    // ---- per-lane constants (ZOH), mode n = sub; fold w = 2C into state ----
    const float dt = expf(log_dt[h]);
    const int hn = h * N2_ + sub;
    const float Ar = -expf(A_real_log[hn]);
    const float Ai = A_imag[hn];
    const float xr = dt * Ar;
    const float xi = dt * Ai;
    const float ex = expf(xr);
    const float cs = cosf(xi);
    const float sn = sinf(xi);
    const float dAr = ex * cs;
    const float dAi = ex * sn;
    // expm1(dtA)/A, cancellation-safe real part of expm1:
    const float sh  = sinf(0.5f * xi);
    const float emr = expm1f(xr) * cs - 2.0f * sh * sh;
    const float emi = ex * sn;
    const float ia  = 1.0f / (Ar * Ar + Ai * Ai);
    const float tr  = (emr * Ar + emi * Ai) * ia;
    const float ti  = (emi * Ar - emr * Ai) * ia;
    const float Br = B_re[hn], Bi = B_im[hn];
    const float dBr = Br * tr - Bi * ti;
    const float dBi = Br * ti + Bi * tr;
    const float wr = 2.0f * C_re[hn];
    const float wi = 2.0f * C_im[hn];

    v2f dA2, dB2v;
    dA2.x  = dAr;               dA2.y  = dAi;
    dB2v.x = wr * dBr - wi * dBi;
    dB2v.y = wr * dBi + wi * dBr;

    const float Dh = Dv[h];           // lane covers (pair q, t=t0+sub) at flush

    const float* __restrict__ xrow = x     + (size_t)bblk * L_ * H_ + h0;
    float*       __restrict__ yrow = out_y + (size_t)bblk * L_ * H_ + h0;

    const int j0 = tid >> 4;          // staging t-offset (0..31)
    const int p0 = tid & 15;          // staging h-offset

    // ---- prologue: stage chunk 0, prefetch chunk 1 ----
    float rx = xrow[(size_t)j0 * H_ + p0];
    ldsX[0][p0 * XSTR + j0] = rx;
    rx = xrow[(size_t)(TC + j0) * H_ + p0];
    __syncthreads();

    v2f u; u.x = 0.f; u.y = 0.f;      // u = 2C * state (folded projection)

    const bool b1 = (sub & 1), b2 = (sub & 2), b4 = (sub & 4),
               b8 = (sub & 8), b16 = (sub & 16);

    for (int c = 0; c < NCHUNK; ++c) {
        const int cb = c & 1;

        // stage next chunk's x; issue global load for chunk c+2
        if (c + 1 < NCHUNK) ldsX[cb ^ 1][p0 * XSTR + j0] = rx;
        if (c + 2 < NCHUNK) rx = xrow[(size_t)((c + 2) * TC + j0) * H_ + p0];

        // pull this chunk's 32 x-values into registers (broadcast b128 reads)
        v4f a[8];
        const v4f* xq = (const v4f*)&ldsX[cb][q * XSTR];
#pragma unroll
        for (int i = 0; i < 8; ++i) a[i] = xq[i];

        // ---- serial scan, TC steps: 3 packed VOP3P ops + 1 capture each ----
        float p[TC];
#pragma unroll
        for (int j = 0; j < TC; ++j) {
            const v4f t4 = a[j >> 2];
            // x-pair holding xv in half (j&1): elements (0,1) or (2,3)
            v2f xp;
            if (j & 2) { xp = __builtin_shufflevector(t4, t4, 2, 3); }
            else       { xp = __builtin_shufflevector(t4, t4, 0, 1); }

            v2f m, t, un;
            if (j & 1) {
                // m = (dB2r*xv, dB2i*xv), xv = xp.hi broadcast
                asm("v_pk_mul_f32 %0, %1, %2 op_sel:[0,1] op_sel_hi:[1,1]"
                    : "=v"(m) : "v"(dB2v), "v"(xp));
            } else {
                // xv = xp.lo broadcast
                asm("v_pk_mul_f32 %0, %1, %2 op_sel:[0,0] op_sel_hi:[1,0]"
                    : "=v"(m) : "v"(dB2v), "v"(xp));
            }
            // t = (-dAi*ui + m.lo,  dAi*ur + m.hi)
            asm("v_pk_fma_f32 %0, %1, %2, %3 op_sel:[1,1,0] op_sel_hi:[1,0,1] neg_lo:[1,0,0]"
                : "=v"(t) : "v"(dA2), "v"(u), "v"(m));
            // u' = (dAr*ur + t.lo,  dAr*ui + t.hi)
            asm("v_pk_fma_f32 %0, %1, %2, %3 op_sel:[0,0,0] op_sel_hi:[0,1,1]"
                : "=v"(un) : "v"(dA2), "v"(u), "v"(t));
            u = un;
            p[j] = u.x;                // Re(u) = this mode's y-contribution
        }

        // ---- 5-stage distributed transpose-reduce across the 32 lanes ----
#pragma unroll
        for (int j = 0; j < 32; j += 2) {
            const float keep = b1 ? p[j + 1] : p[j];
            const float send = b1 ? p[j] : p[j + 1];
            p[j] = keep + bfly1(send);
        }
#pragma unroll
        for (int j = 0; j < 32; j += 4) {
            const float keep = b2 ? p[j + 2] : p[j];
            const float send = b2 ? p[j] : p[j + 2];
            p[j] = keep + bfly2(send);
        }
#pragma unroll
        for (int j = 0; j < 32; j += 8) {
            const float keep = b4 ? p[j + 4] : p[j];
            const float send = b4 ? p[j] : p[j + 4];
            p[j] = keep + bflyswz<4>(send);
        }
#pragma unroll
        for (int j = 0; j < 32; j += 16) {
            const float keep = b8 ? p[j + 8] : p[j];
            const float send = b8 ? p[j] : p[j + 8];
            p[j] = keep + bflyswz<8>(send);
        }
        {
            const float keep = b16 ? p[16] : p[0];
            const float send = b16 ? p[0] : p[16];
            p[0] = keep + bflyswz<16>(send);
        }

        // ---- epilogue: lane (q, t=t0+sub): + D*x, GELU, LDS transpose ----
        {
            const float xv = ldsX[cb][q * XSTR + sub];
            const float y  = fmaf(Dh, xv, p[0]);
            // gelu(y) ~= y * sigmoid(2*sqrt(2/pi)*(y + 0.044715 y^3))
            // exp2-folded: g = y / (1 + exp2(y*(-cb*y^2 - ca)))
            const float y2  = y * y;
            const float arg = y * fmaf(-0.10294502f, y2, -2.30218425f);
            const float e   = __builtin_amdgcn_exp2f(arg);
            const float g   = y * __builtin_amdgcn_rcpf(1.0f + e);
            ldsYT[cb][q * YTSTR + sub] = g;
        }
        __syncthreads();   // YT visible; next x-tile staged; prev reads done

        // coalesced y store: thread e -> (t = e>>4, p = e&15)
        yrow[(size_t)(c * TC + (tid >> 4)) * H_ + (tid & 15)] =
            ldsYT[cb][(tid & 15) * YTSTR + (tid >> 4)];
    }

    // ---- final state: s = u * conj(w) / |w|^2, planar re/im ----
    const float iw = 1.0f / (wr * wr + wi * wi);
    const float sr = (u.x * wr + u.y * wi) * iw;
    const float si = (u.y * wr - u.x * wi) * iw;
    st_re[(size_t)pair * N2_ + sub] = sr;
    st_im[(size_t)pair * N2_ + sub] = si;
}

extern "C" void kernel_launch(void* const* d_in, const int* in_sizes, int n_in,
                              void* d_out, int out_size, void* d_ws, size_t ws_size,
                              hipStream_t stream) {
    (void)in_sizes; (void)n_in; (void)d_ws; (void)ws_size; (void)out_size;
    const float* x    = (const float*)d_in[0];
    const float* ldt  = (const float*)d_in[1];
    const float* Arl  = (const float*)d_in[2];
    const float* Aim  = (const float*)d_in[3];
    const float* Bre  = (const float*)d_in[4];
    const float* Bim  = (const float*)d_in[5];
    const float* Cre  = (const float*)d_in[6];
    const float* Cim  = (const float*)d_in[7];
    const float* Dv   = (const float*)d_in[8];
    float* out = (float*)d_out;
    float* st_re = out + (size_t)B_ * L_ * H_;       // ys first
    float* st_im = st_re + (size_t)B_ * H_ * N2_;    // then imag plane

    dim3 grid(B_ * H_ / PPB);   // 256 blocks (1 per CU), 8 waves each
    dim3 block(THREADS);        // 512 threads
    hipLaunchKernelGGL(s4d_scan_kernel, grid, block, 0, stream,
                       x, ldt, Arl, Aim, Bre, Bim, Cre, Cim, Dv, out, st_re, st_im);
}